// Round 1
// baseline (684.891 us; speedup 1.0000x reference)
//
#include <hip/hip_runtime.h>

#define D_IN  512
#define D_ENC 256
#define MAX_LAMB 10000

// ---------------- kernel 1: q = W_user^T u ; v = W_item @ q ----------------
__global__ void encode_kernel(const float* __restrict__ u,
                              const float* __restrict__ Wu,
                              const float* __restrict__ Wi,
                              float* __restrict__ v) {
    __shared__ float us[D_IN];
    __shared__ float q[D_ENC];
    const int tid = threadIdx.x;            // 256 threads
    for (int i = tid; i < D_IN; i += 256) us[i] = u[i];
    __syncthreads();
    // q[tid] = sum_i u[i] * Wu[i][tid]  (coalesced across threads)
    float acc = 0.f;
    for (int i = 0; i < D_IN; ++i) acc += us[i] * Wu[i * D_ENC + tid];
    q[tid] = acc;
    __syncthreads();
    // v[r] = sum_j Wi[r][j] * q[j]
    for (int r = tid; r < D_IN; r += 256) {
        const float* row = Wi + (size_t)r * D_ENC;
        float a = 0.f;
        for (int j = 0; j < D_ENC; j += 4) {
            float4 w = *(const float4*)(row + j);
            a += w.x * q[j] + w.y * q[j + 1] + w.z * q[j + 2] + w.w * q[j + 3];
        }
        v[r] = a;
    }
}

// ---------------- kernel 2: sims[i] = items[i] . v  (one wave per row) -----
__global__ void __launch_bounds__(256)
sims_kernel(const float* __restrict__ items,
            const float* __restrict__ v,
            float* __restrict__ sims, int n) {
    const int lane  = threadIdx.x & 63;
    const int wave  = (blockIdx.x * blockDim.x + threadIdx.x) >> 6;
    const int nwave = (gridDim.x * blockDim.x) >> 6;
    // per-lane v fragment: 8 contiguous floats, loaded once
    const float4 v0 = *(const float4*)(v + lane * 8);
    const float4 v1 = *(const float4*)(v + lane * 8 + 4);
    for (int row = wave; row < n; row += nwave) {
        const float* p = items + (size_t)row * D_IN + lane * 8;
        const float4 a0 = *(const float4*)(p);
        const float4 a1 = *(const float4*)(p + 4);
        float s = a0.x * v0.x + a0.y * v0.y + a0.z * v0.z + a0.w * v0.w
                + a1.x * v1.x + a1.y * v1.y + a1.z * v1.z + a1.w * v1.w;
        #pragma unroll
        for (int off = 32; off >= 1; off >>= 1) s += __shfl_xor(s, off);
        if (lane == 0) sims[row] = s;
    }
}

// ---------------- kernel 3: exact rank-select of sampled sims --------------
__device__ __forceinline__ unsigned f2key(float f) {
    unsigned u = __float_as_uint(f);
    return (u & 0x80000000u) ? ~u : (u | 0x80000000u);
}

__global__ void threshold_kernel(const float* __restrict__ sims,
                                 const int* __restrict__ sample_idx,
                                 int lamb, int rank,
                                 float* __restrict__ t_out) {
    __shared__ unsigned keys[MAX_LAMB];
    __shared__ unsigned hist[256];
    __shared__ unsigned s_prefix, s_mask;
    __shared__ int s_rank;
    const int tid = threadIdx.x;            // 256 threads
    for (int s = tid; s < lamb; s += 256)
        keys[s] = f2key(sims[sample_idx[s]]);
    if (tid == 0) { s_prefix = 0u; s_mask = 0u; s_rank = rank; }
    __syncthreads();
    for (int shift = 24; shift >= 0; shift -= 8) {
        hist[tid] = 0u;
        __syncthreads();
        const unsigned pmask = s_mask, pfx = s_prefix;
        for (int s = tid; s < lamb; s += 256) {
            unsigned key = keys[s];
            if ((key & pmask) == pfx)
                atomicAdd(&hist[(key >> shift) & 255u], 1u);
        }
        __syncthreads();
        if (tid == 0) {
            int running = 0, r = s_rank;
            for (int b = 0; b < 256; ++b) {
                int h = (int)hist[b];
                if (running + h > r) {
                    s_prefix = pfx | ((unsigned)b << shift);
                    s_mask   = pmask | (0xFFu << shift);
                    s_rank   = r - running;
                    break;
                }
                running += h;
            }
        }
        __syncthreads();
    }
    if (tid == 0) {
        unsigned key = s_prefix;
        unsigned u = (key & 0x80000000u) ? (key & 0x7FFFFFFFu) : ~key;
        *t_out = __uint_as_float(u);
    }
}

// ---------------- kernel 4: selected = where(sims > t, sims, 0) ------------
__global__ void filter_kernel(const float* __restrict__ sims,
                              const float* __restrict__ t_ptr,
                              float* __restrict__ out, int n) {
    const float t = *t_ptr;
    const int stride4 = gridDim.x * blockDim.x * 4;
    for (int j = (blockIdx.x * blockDim.x + threadIdx.x) * 4; j < n; j += stride4) {
        float4 s = *(const float4*)(sims + j);
        float4 o;
        o.x = (s.x > t) ? s.x : 0.f;
        o.y = (s.y > t) ? s.y : 0.f;
        o.z = (s.z > t) ? s.z : 0.f;
        o.w = (s.w > t) ? s.w : 0.f;
        *(float4*)(out + j) = o;
    }
}

extern "C" void kernel_launch(void* const* d_in, const int* in_sizes, int n_in,
                              void* d_out, int out_size, void* d_ws, size_t ws_size,
                              hipStream_t stream) {
    const float* u     = (const float*)d_in[0];
    const float* items = (const float*)d_in[1];
    const float* Wu    = (const float*)d_in[2];
    const float* Wi    = (const float*)d_in[3];
    const int*   sidx  = (const int*)d_in[4];

    const int d_in_dim = in_sizes[0];               // 512
    const int n        = in_sizes[1] / d_in_dim;    // 200000
    const int lamb     = in_sizes[4];               // 10000
    const int K        = 1000;                      // reference static constant
    long ti = (long)K * lamb / n;
    if (ti > lamb - 1) ti = lamb - 1;               // == 50

    float* ws    = (float*)d_ws;
    float* v     = ws;              // 512 floats
    float* t     = ws + 512;        // 1 float
    float* sims  = ws + 1024;       // n floats

    encode_kernel<<<1, 256, 0, stream>>>(u, Wu, Wi, v);
    sims_kernel<<<2048, 256, 0, stream>>>(items, v, sims, n);
    threshold_kernel<<<1, 256, 0, stream>>>(sims, sidx, lamb, (int)ti, t);
    filter_kernel<<<(n / 4 + 255) / 256, 256, 0, stream>>>(sims, t, (float*)d_out, n);
}